// Round 9
// baseline (242.770 us; speedup 1.0000x reference)
//
#include <hip/hip_runtime.h>

#define DIM 128
#define NSHARD 8

typedef __attribute__((ext_vector_type(2))) float f32x2;
typedef __attribute__((ext_vector_type(4))) _Float16 half4;
typedef __attribute__((ext_vector_type(8))) _Float16 half8;
typedef __attribute__((ext_vector_type(4))) float f32x4;

#define HP 136  // fp16 tile row stride (halfs): 128 + 8 pad (2-way = free)
#define UP 264  // fp16 tile row stride (halfs): 256 + 8 pad

__device__ __forceinline__ unsigned char to_fp8(float v) {
  return (unsigned char)(__builtin_amdgcn_cvt_pk_fp8_f32(v, v, 0, false) & 0xff);
}

// ------- fp32 -> fp16 conversion of all weights + zero cnt/stats -------------
__global__ __launch_bounds__(256) void conv_wall(const float* __restrict__ Wk,
    const float* __restrict__ Wv, const float* __restrict__ Wo,
    const float* __restrict__ W1, const float* __restrict__ W2,
    _Float16* __restrict__ Wkh, _Float16* __restrict__ Wvh,
    _Float16* __restrict__ Woh, _Float16* __restrict__ W1h,
    _Float16* __restrict__ W2h, int* __restrict__ cnt, float* __restrict__ stats,
    int N) {
  int i = blockIdx.x * 256 + threadIdx.x;
  int nth = gridDim.x * 256;
  if (i < 16384) Wkh[i] = (_Float16)Wk[i];
  else if (i < 32768) Wvh[i - 16384] = (_Float16)Wv[i - 16384];
  else if (i < 49152) Woh[i - 32768] = (_Float16)Wo[i - 32768];
  else if (i < 81920) W1h[i - 49152] = (_Float16)W1[i - 49152];
  else if (i < 114688) W2h[i - 81920] = (_Float16)W2[i - 81920];
  for (int j = i; j < N * NSHARD; j += nth) cnt[j] = 0;
  if (i < 512) stats[i] = 0.f;
}

// ---------- CSR build: hist with rank capture, counters sharded x8 ----------
__global__ __launch_bounds__(256) void hist_rank(const int* __restrict__ ei,
    int* __restrict__ cnt, int* __restrict__ rank, int N, int E) {
  int e = blockIdx.x * 256 + threadIdx.x;
  if (e < E) rank[e] = atomicAdd(&cnt[(e & (NSHARD - 1)) * N + ei[E + e]], 1);
}

__global__ __launch_bounds__(256) void scanA(const int* __restrict__ cnt,
    int* __restrict__ rs, int* __restrict__ bsum, int N) {
  __shared__ int s[256];
  int t = threadIdx.x;
  int i = blockIdx.x * 256 + t;
  int v = 0;
  if (i < N)
#pragma unroll
    for (int sh = 0; sh < NSHARD; sh++) v += cnt[sh * N + i];
  s[t] = v;
  __syncthreads();
  for (int off = 1; off < 256; off <<= 1) {
    int add = (t >= off) ? s[t - off] : 0;
    __syncthreads();
    s[t] += add;
    __syncthreads();
  }
  if (i < N) rs[i] = s[t] - v;
  if (t == 255) bsum[blockIdx.x] = s[t];
}

// scanB folded in: every block re-scans the <=256 block sums in LDS.
__global__ __launch_bounds__(256) void scanBC(int* __restrict__ rs,
    const int* __restrict__ bsum, const int* __restrict__ cnt,
    int* __restrict__ rs_shard, int nblk, int N, int E) {
  __shared__ int s[256];
  __shared__ int ex[256];
  int t = threadIdx.x;
  int v = (t < nblk) ? bsum[t] : 0;
  s[t] = v;
  __syncthreads();
  for (int off = 1; off < 256; off <<= 1) {
    int add = (t >= off) ? s[t - off] : 0;
    __syncthreads();
    s[t] += add;
    __syncthreads();
  }
  ex[t] = s[t] - v;  // exclusive prefix of bsum
  __syncthreads();
  int boff = ex[blockIdx.x];
  int i = blockIdx.x * 256 + t;
  if (i < N) {
    int b = rs[i] + boff;
    rs[i] = b;
#pragma unroll
    for (int sh = 0; sh < NSHARD; sh++) {
      rs_shard[sh * N + i] = b;
      b += cnt[sh * N + i];
    }
  }
  if (i == 0) rs[N] = E;
}

// ------ merged: atomic-free scatter (blocks >= kvb) + KV projection ---------
// Also emits x16 (fp16 copy of x) as a side product of the staging pass:
// attn_agg q-loads and o_proj residual then read half the bytes.
__global__ __launch_bounds__(256) void scatter_kv(const int* __restrict__ ei,
    const int* __restrict__ rs_shard, const int* __restrict__ rank,
    int* __restrict__ esrc, const float* __restrict__ x,
    const _Float16* __restrict__ Wkh, const float* __restrict__ bk,
    const _Float16* __restrict__ Wvh, const float* __restrict__ bv,
    unsigned char* __restrict__ KV8, _Float16* __restrict__ x16,
    int kvb, int N, int E) {
  __shared__ _Float16 xs[64 * HP];  // 17.4 KB (kv blocks only)
  int tid = threadIdx.x;
  if ((int)blockIdx.x >= kvb) {
    int e = ((int)blockIdx.x - kvb) * 256 + tid;
    if (e < E)
      esrc[rs_shard[(e & (NSHARD - 1)) * N + ei[E + e]] + rank[e]] = ei[e];
    return;
  }
  int base = blockIdx.x * 64;
  int lane = tid & 63, w = tid >> 6;
  int l15 = lane & 15, quad = lane >> 4;

  for (int i = tid; i < 64 * 32; i += 256) {
    int m = i >> 5, c4 = i & 31;
    float4 tv = ((const float4*)x)[(size_t)(base + m) * 32 + c4];
    half4 hv;
    hv.x = (_Float16)tv.x; hv.y = (_Float16)tv.y;
    hv.z = (_Float16)tv.z; hv.w = (_Float16)tv.w;
    *(half4*)&xs[m * HP + c4 * 4] = hv;
    *(half4*)&x16[(size_t)(base + m) * DIM + c4 * 4] = hv;
  }
  __syncthreads();

  half8 afr[4][4];
#pragma unroll
  for (int mt = 0; mt < 4; mt++)
#pragma unroll
    for (int ks = 0; ks < 4; ks++)
      afr[mt][ks] = *(const half8*)&xs[(mt * 16 + l15) * HP + ks * 32 + quad * 8];

  const _Float16* W = (w < 2) ? Wkh : Wvh;
  const float* bias = (w < 2) ? bk : bv;
  int voff = (w < 2) ? 0 : 4;
  int c0 = (w & 1) * 64;

#pragma unroll
  for (int nt = 0; nt < 4; nt++) {
    int f = c0 + nt * 16 + l15;
    half8 bfr[4];
#pragma unroll
    for (int ks = 0; ks < 4; ks++)
      bfr[ks] = *(const half8*)&W[(size_t)f * 128 + ks * 32 + quad * 8];
    f32x4 acc[4];
#pragma unroll
    for (int mt = 0; mt < 4; mt++) acc[mt] = (f32x4){0.f, 0.f, 0.f, 0.f};
#pragma unroll
    for (int ks = 0; ks < 4; ks++)
#pragma unroll
      for (int mt = 0; mt < 4; mt++)
        acc[mt] = __builtin_amdgcn_mfma_f32_16x16x32_f16(afr[mt][ks], bfr[ks],
                                                          acc[mt], 0, 0, 0);
    float bb = bias[f];
    int fo = (f >> 2) * 8 + (f & 3) + voff;  // interleaved byte offset
#pragma unroll
    for (int mt = 0; mt < 4; mt++)
#pragma unroll
      for (int r = 0; r < 4; r++)
        KV8[(size_t)(base + mt * 16 + quad * 4 + r) * 256 + fo] =
            to_fp8(acc[mt][r] + bb);
  }
}

// ---------------- fused attention aggregate: one wave per dst node ----------
// 16 lanes per edge (uint4 = 16B/lane): 4 edges in flight per wave (was 2),
// halved per-edge load/exp/shuffle instruction counts. HEAD_DIM=16 -> a head
// is a lane PAIR: score reduce is a single shfl_xor(1).
__global__ __launch_bounds__(256) void attn_agg(const unsigned char* __restrict__ KV8,
    const _Float16* __restrict__ x16, const int* __restrict__ rs,
    const int* __restrict__ esrc, _Float16* __restrict__ attn16, int N) {
  int wave = threadIdx.x >> 6, lane = threadIdx.x & 63;
  int n = blockIdx.x * 4 + wave;
  if (n >= N) return;
  int c = lane & 15, h = lane >> 4;  // lane c: features [8c,8c+8); h: edge slot
  half8 qh = *(const half8*)&x16[(size_t)n * DIM + 8 * c];
  float q0 = (float)qh[0], q1 = (float)qh[1], q2 = (float)qh[2],
        q3 = (float)qh[3], q4 = (float)qh[4], q5 = (float)qh[5],
        q6 = (float)qh[6], q7 = (float)qh[7];
  int beg = rs[n], end = rs[n + 1];
  float a0 = 0.f, a1 = 0.f, a2 = 0.f, a3 = 0.f;
  float a4 = 0.f, a5 = 0.f, a6 = 0.f, a7 = 0.f, dloc = 0.f;
  for (int e = beg + h; e < end; e += 16) {
    bool hh[4];
    int ss[4];
#pragma unroll
    for (int u = 0; u < 4; u++) hh[u] = (e + 4 * u) < end;
    ss[0] = esrc[e];
#pragma unroll
    for (int u = 1; u < 4; u++) ss[u] = hh[u] ? esrc[e + 4 * u] : ss[0];
    uint4 kv[4];
#pragma unroll
    for (int u = 0; u < 4; u++)
      kv[u] = *(const uint4*)&KV8[(size_t)ss[u] * 256 + 16 * c];
    float p[4];
#pragma unroll
    for (int u = 0; u < 4; u++) {
      // kv.x=K[8c..8c+3] kv.y=V[8c..8c+3] kv.z=K[8c+4..] kv.w=V[8c+4..]
      f32x2 k01 = __builtin_amdgcn_cvt_pk_f32_fp8(kv[u].x, false);
      f32x2 k23 = __builtin_amdgcn_cvt_pk_f32_fp8(kv[u].x, true);
      f32x2 k45 = __builtin_amdgcn_cvt_pk_f32_fp8(kv[u].z, false);
      f32x2 k67 = __builtin_amdgcn_cvt_pk_f32_fp8(kv[u].z, true);
      p[u] = k01[0] * q0 + k01[1] * q1 + k23[0] * q2 + k23[1] * q3 +
             k45[0] * q4 + k45[1] * q5 + k67[0] * q6 + k67[1] * q7;
    }
    // head = lane pair (c, c^1): one shuffle completes the 16-dim dot
#pragma unroll
    for (int u = 0; u < 4; u++) p[u] += __shfl_xor(p[u], 1);
#pragma unroll
    for (int u = 0; u < 4; u++) {
      float ev = hh[u] ? __expf(p[u] * 0.25f) : 0.f;
      dloc += ev;
      f32x2 v01 = __builtin_amdgcn_cvt_pk_f32_fp8(kv[u].y, false);
      f32x2 v23 = __builtin_amdgcn_cvt_pk_f32_fp8(kv[u].y, true);
      f32x2 v45 = __builtin_amdgcn_cvt_pk_f32_fp8(kv[u].w, false);
      f32x2 v67 = __builtin_amdgcn_cvt_pk_f32_fp8(kv[u].w, true);
      a0 += ev * v01[0]; a1 += ev * v01[1];
      a2 += ev * v23[0]; a3 += ev * v23[1];
      a4 += ev * v45[0]; a5 += ev * v45[1];
      a6 += ev * v67[0]; a7 += ev * v67[1];
    }
  }
  // merge the 4 edge-slot groups (same c across h)
  dloc += __shfl_xor(dloc, 16); dloc += __shfl_xor(dloc, 32);
  a0 += __shfl_xor(a0, 16); a0 += __shfl_xor(a0, 32);
  a1 += __shfl_xor(a1, 16); a1 += __shfl_xor(a1, 32);
  a2 += __shfl_xor(a2, 16); a2 += __shfl_xor(a2, 32);
  a3 += __shfl_xor(a3, 16); a3 += __shfl_xor(a3, 32);
  a4 += __shfl_xor(a4, 16); a4 += __shfl_xor(a4, 32);
  a5 += __shfl_xor(a5, 16); a5 += __shfl_xor(a5, 32);
  a6 += __shfl_xor(a6, 16); a6 += __shfl_xor(a6, 32);
  a7 += __shfl_xor(a7, 16); a7 += __shfl_xor(a7, 32);
  if (h == 0) {
    float inv = 1.0f / (dloc + 1e-16f);
    half8 o;
    o[0] = (_Float16)(a0 * inv); o[1] = (_Float16)(a1 * inv);
    o[2] = (_Float16)(a2 * inv); o[3] = (_Float16)(a3 * inv);
    o[4] = (_Float16)(a4 * inv); o[5] = (_Float16)(a5 * inv);
    o[6] = (_Float16)(a6 * inv); o[7] = (_Float16)(a7 * inv);
    *(half8*)&attn16[(size_t)n * DIM + 8 * c] = o;
  }
}

// ------- O-projection + residual + BN1 stats; t fp16; x16 residual ----------
__global__ __launch_bounds__(512) void o_proj_mfma(const _Float16* __restrict__ attn16,
    const _Float16* __restrict__ x16, const _Float16* __restrict__ Woh,
    const float* __restrict__ bo, _Float16* __restrict__ t16,
    float* __restrict__ stats, int N) {
  __shared__ _Float16 as16[64 * HP];  // 17.4 KB
  int tid = threadIdx.x;
  int base = blockIdx.x * 64;
  int lane = tid & 63, w = tid >> 6;  // w in [0,8)
  int l15 = lane & 15, quad = lane >> 4;

  for (int i = tid; i < 64 * 16; i += 512) {
    int m = i >> 4, c8 = i & 15;
    *(half8*)&as16[m * HP + c8 * 8] =
        ((const half8*)attn16)[(size_t)(base + m) * 16 + c8];
  }
  __syncthreads();

  half8 afr[4][4];
#pragma unroll
  for (int mt = 0; mt < 4; mt++)
#pragma unroll
    for (int ks = 0; ks < 4; ks++)
      afr[mt][ks] = *(const half8*)&as16[(mt * 16 + l15) * HP + ks * 32 + quad * 8];

  int c0 = w * 16;  // 16 features per wave
  f32x4 acc[4];
#pragma unroll
  for (int mt = 0; mt < 4; mt++) acc[mt] = (f32x4){0.f, 0.f, 0.f, 0.f};
#pragma unroll
  for (int ks = 0; ks < 4; ks++) {
    half8 b = *(const half8*)&Woh[(size_t)(c0 + l15) * 128 + ks * 32 + quad * 8];
#pragma unroll
    for (int mt = 0; mt < 4; mt++)
      acc[mt] = __builtin_amdgcn_mfma_f32_16x16x32_f16(afr[mt][ks], b, acc[mt],
                                                        0, 0, 0);
  }

  int f = c0 + l15;
  float bb = bo[f];
  float s = 0.f, q = 0.f;
#pragma unroll
  for (int mt = 0; mt < 4; mt++) {
#pragma unroll
    for (int r = 0; r < 4; r++) {
      int row = mt * 16 + quad * 4 + r;
      float tv = acc[mt][r] + bb + (float)x16[(size_t)(base + row) * DIM + f];
      t16[(size_t)(base + row) * DIM + f] = (_Float16)tv;
      s += tv;
      q += tv * tv;
    }
  }
  s += __shfl_xor(s, 16);
  s += __shfl_xor(s, 32);
  q += __shfl_xor(q, 16);
  q += __shfl_xor(q, 32);
  if (quad == 0) {
    atomicAdd(&stats[f], s);
    atomicAdd(&stats[128 + f], q);
  }
}

// ------- fused FFN via MFMA; R7-identical -----------------------------------
__global__ __launch_bounds__(512) void ffn_mfma(const _Float16* __restrict__ t16,
    const float* __restrict__ stats1, const float* __restrict__ g1,
    const float* __restrict__ bb1, const _Float16* __restrict__ W1h,
    const float* __restrict__ b1, const _Float16* __restrict__ W2h,
    const float* __restrict__ b2, _Float16* __restrict__ z16,
    float* __restrict__ stats2, float invN, int N) {
  __shared__ _Float16 hs[64 * HP];  // 17.4 KB
  __shared__ _Float16 us[64 * UP];  // 33.8 KB
  __shared__ float cf[256];
  int tid = threadIdx.x;
  int base = blockIdx.x * 64;
  int lane = tid & 63, w = tid >> 6;  // w in [0,8)
  int l15 = lane & 15, quad = lane >> 4;

  if (tid < 128) {
    float mu = stats1[tid] * invN;
    float var = stats1[128 + tid] * invN - mu * mu;
    float a = rsqrtf(var + 1e-5f) * g1[tid];
    cf[tid] = a;
    cf[128 + tid] = bb1[tid] - mu * a;
  }
  __syncthreads();

  for (int i = tid; i < 64 * 16; i += 512) {
    int m = i >> 4, c8 = i & 15;
    half8 tv = ((const half8*)t16)[(size_t)(base + m) * 16 + c8];
    half8 hv;
#pragma unroll
    for (int j = 0; j < 8; j++) {
      int f = c8 * 8 + j;
      hv[j] = (_Float16)((float)tv[j] * cf[f] + cf[128 + f]);
    }
    *(half8*)&hs[m * HP + c8 * 8] = hv;
  }
  __syncthreads();

  int n0 = w * 32;  // 32 u-columns per wave
  half8 afr[4][4];
#pragma unroll
  for (int mt = 0; mt < 4; mt++)
#pragma unroll
    for (int ks = 0; ks < 4; ks++)
      afr[mt][ks] = *(const half8*)&hs[(mt * 16 + l15) * HP + ks * 32 + quad * 8];

#pragma unroll
  for (int nt = 0; nt < 2; nt++) {
    int n = n0 + nt * 16 + l15;
    half8 bfr[4];
#pragma unroll
    for (int ks = 0; ks < 4; ks++)
      bfr[ks] = *(const half8*)&W1h[(size_t)n * 128 + ks * 32 + quad * 8];
    f32x4 acc[4];
#pragma unroll
    for (int mt = 0; mt < 4; mt++) acc[mt] = (f32x4){0.f, 0.f, 0.f, 0.f};
#pragma unroll
    for (int ks = 0; ks < 4; ks++)
#pragma unroll
      for (int mt = 0; mt < 4; mt++)
        acc[mt] = __builtin_amdgcn_mfma_f32_16x16x32_f16(afr[mt][ks], bfr[ks],
                                                          acc[mt], 0, 0, 0);
    float bias = b1[n];
#pragma unroll
    for (int mt = 0; mt < 4; mt++)
#pragma unroll
      for (int r = 0; r < 4; r++)
        us[(mt * 16 + quad * 4 + r) * UP + n] =
            (_Float16)fmaxf(acc[mt][r] + bias, 0.f);
  }
  __syncthreads();

  int n2 = w * 16;  // 16 z-columns per wave
  f32x4 acc2[4];
#pragma unroll
  for (int mt = 0; mt < 4; mt++) acc2[mt] = (f32x4){0.f, 0.f, 0.f, 0.f};
  for (int ks = 0; ks < 8; ks++) {
    half8 a[4];
#pragma unroll
    for (int mt = 0; mt < 4; mt++)
      a[mt] = *(const half8*)&us[(mt * 16 + l15) * UP + ks * 32 + quad * 8];
    half8 b = *(const half8*)&W2h[(size_t)(n2 + l15) * 256 + ks * 32 + quad * 8];
#pragma unroll
    for (int mt = 0; mt < 4; mt++)
      acc2[mt] = __builtin_amdgcn_mfma_f32_16x16x32_f16(a[mt], b, acc2[mt],
                                                         0, 0, 0);
  }

  int f = n2 + l15;
  float bz = b2[f];
  float s = 0.f, q = 0.f;
#pragma unroll
  for (int mt = 0; mt < 4; mt++) {
#pragma unroll
    for (int r = 0; r < 4; r++) {
      int row = mt * 16 + quad * 4 + r;
      float hv = (float)hs[row * HP + f];
      float zv = hv + acc2[mt][r] + bz;
      z16[(size_t)(base + row) * DIM + f] = (_Float16)zv;
      s += zv;
      q += zv * zv;
    }
  }
  s += __shfl_xor(s, 16);
  s += __shfl_xor(s, 32);
  q += __shfl_xor(q, 16);
  q += __shfl_xor(q, 32);
  if (quad == 0) {
    atomicAdd(&stats2[f], s);
    atomicAdd(&stats2[128 + f], q);
  }
}

// -------- final BN2 apply from fp16 z; coef derived per-block ----------------
__global__ __launch_bounds__(256) void final_apply(const _Float16* __restrict__ z16,
    const float* __restrict__ stats2, const float* __restrict__ g2,
    const float* __restrict__ bb2, float* __restrict__ out, float invN,
    int total8) {
  __shared__ float cf[256];
  int tid = threadIdx.x;
  if (tid < 128) {
    float mu = stats2[tid] * invN;
    float var = stats2[128 + tid] * invN - mu * mu;
    float a = rsqrtf(var + 1e-5f) * g2[tid];
    cf[tid] = a;
    cf[128 + tid] = bb2[tid] - mu * a;
  }
  __syncthreads();
  int i = blockIdx.x * 256 + tid;
  if (i >= total8) return;
  int f0 = (i * 8) & 127;
  half8 zv = ((const half8*)z16)[i];
  float4 o1, o2;
  o1.x = (float)zv[0] * cf[f0 + 0] + cf[128 + f0 + 0];
  o1.y = (float)zv[1] * cf[f0 + 1] + cf[128 + f0 + 1];
  o1.z = (float)zv[2] * cf[f0 + 2] + cf[128 + f0 + 2];
  o1.w = (float)zv[3] * cf[f0 + 3] + cf[128 + f0 + 3];
  o2.x = (float)zv[4] * cf[f0 + 4] + cf[128 + f0 + 4];
  o2.y = (float)zv[5] * cf[f0 + 5] + cf[128 + f0 + 5];
  o2.z = (float)zv[6] * cf[f0 + 6] + cf[128 + f0 + 6];
  o2.w = (float)zv[7] * cf[f0 + 7] + cf[128 + f0 + 7];
  ((float4*)out)[2 * i] = o1;
  ((float4*)out)[2 * i + 1] = o2;
}

extern "C" void kernel_launch(void* const* d_in, const int* in_sizes, int n_in,
                              void* d_out, int out_size, void* d_ws, size_t ws_size,
                              hipStream_t stream) {
  const float* x = (const float*)d_in[0];
  const int* ei = (const int*)d_in[1];
  const float* Wk = (const float*)d_in[2];
  const float* bk = (const float*)d_in[3];
  const float* Wv = (const float*)d_in[4];
  const float* bv = (const float*)d_in[5];
  const float* Wo = (const float*)d_in[6];
  const float* bo = (const float*)d_in[7];
  const float* bn1_g = (const float*)d_in[8];
  const float* bn1_b = (const float*)d_in[9];
  const float* W1 = (const float*)d_in[10];
  const float* b1 = (const float*)d_in[11];
  const float* W2 = (const float*)d_in[12];
  const float* b2 = (const float*)d_in[13];
  const float* bn2_g = (const float*)d_in[14];
  const float* bn2_b = (const float*)d_in[15];
  float* out = (float*)d_out;

  int N = in_sizes[0] / DIM;   // 40000
  int E = in_sizes[1] / 2;     // 640000

  // workspace layout
  unsigned char* KV8 = (unsigned char*)d_ws;              // 10.25 MB
  _Float16* attn16 = (_Float16*)(KV8 + (size_t)N * 256);  // 10.25 MB
  _Float16* t16 = attn16 + (size_t)N * DIM;               // 10.25 MB
  _Float16* z16 = t16 + (size_t)N * DIM;                  // 10.25 MB
  _Float16* x16 = z16 + (size_t)N * DIM;                  // 10.25 MB
  _Float16* W1h = x16 + (size_t)N * DIM;
  _Float16* W2h = W1h + 32768;
  _Float16* Wkh = W2h + 32768;
  _Float16* Wvh = Wkh + 16384;
  _Float16* Woh = Wvh + 16384;
  float* stats = (float*)(Woh + 16384);      // 512 floats: stats1 | stats2
  int* cnt = (int*)(stats + 512);            // N * NSHARD
  int* rs = cnt + (size_t)N * NSHARD;        // N+1
  int* rs_shard = rs + N + 1;                // N * NSHARD
  int* rank = rs_shard + (size_t)N * NSHARD; // E
  int* esrc = rank + E;                      // E
  int* bsum = esrc + E;                      // up to 256

  int nblk = (N + 255) / 256;                // 157
  int kvb = N / 64;                          // 625
  int sblk = (E + 255) / 256;                // 2500
  float invN = 1.0f / N;
  float* stats2 = stats + 256;

  conv_wall<<<512, 256, 0, stream>>>(Wk, Wv, Wo, W1, W2, Wkh, Wvh, Woh, W1h,
                                     W2h, cnt, stats, N);
  hist_rank<<<sblk, 256, 0, stream>>>(ei, cnt, rank, N, E);
  scanA<<<nblk, 256, 0, stream>>>(cnt, rs, bsum, N);
  scanBC<<<nblk, 256, 0, stream>>>(rs, bsum, cnt, rs_shard, nblk, N, E);
  scatter_kv<<<kvb + sblk, 256, 0, stream>>>(ei, rs_shard, rank, esrc, x, Wkh,
                                             bk, Wvh, bv, KV8, x16, kvb, N, E);
  attn_agg<<<(N + 3) / 4, 256, 0, stream>>>(KV8, x16, rs, esrc, attn16, N);
  o_proj_mfma<<<kvb, 512, 0, stream>>>(attn16, x16, Woh, bo, t16, stats, N);
  ffn_mfma<<<kvb, 512, 0, stream>>>(t16, stats, bn1_g, bn1_b, W1h, b1, W2h, b2,
                                    z16, stats2, invN, N);
  final_apply<<<((N * DIM / 8) + 255) / 256, 256, 0, stream>>>(
      z16, stats2, bn2_g, bn2_b, out, invN, N * DIM / 8);
}